// Round 7
// baseline (628.703 us; speedup 1.0000x reference)
//
#include <hip/hip_runtime.h>

#define EPS 1e-5f
#define PROJ_EPS 1e-5f
#define MAX_TANH_ARG 15.0f

typedef __bf16 bf16x8 __attribute__((ext_vector_type(8)));
typedef float f32x4 __attribute__((ext_vector_type(4)));
typedef float f32x2 __attribute__((ext_vector_type(2)));
typedef unsigned u32x4 __attribute__((ext_vector_type(4)));

__device__ __forceinline__ unsigned short f2bf(float f) {
  unsigned u = __builtin_bit_cast(unsigned, f);
  u += 0x7fffu + ((u >> 16) & 1u);   // round-to-nearest-even
  return (unsigned short)(u >> 16);
}

union BF8 {
  unsigned short u[8];
  bf16x8 v;
  uint4 q;
};

// ---------------------------------------------------------------------------
// prep: W[layer][k][n] -> bf16 MFMA B-frag order.
// ---------------------------------------------------------------------------
__global__ __launch_bounds__(256) void prep_kernel(
    const float* __restrict__ W, unsigned short* __restrict__ wpack) {
  const int tid = blockIdx.x * 256 + threadIdx.x;
  if (tid >= 4096) return;
  const int l = tid & 63;
  const int s = (tid >> 6) & 3;
  const int tt = (tid >> 8) & 7;
  const int layer = tid >> 11;
  const int q2 = l >> 4;
  const int n = tt * 16 + (l & 15);
  unsigned short* dst = wpack + ((size_t)((layer * 32 + tt * 4 + s) * 64 + l)) * 8;
  const float* src = W + (size_t)layer * 16384;
#pragma unroll
  for (int j = 0; j < 8; ++j) {
    const int k = s * 32 + q2 * 8 + j;
    dst[j] = f2bf(src[(size_t)k * 128 + n]);
  }
}

// ---------------------------------------------------------------------------
// stage: edges pack (u16 id | f16 w) + x~ = mask^2 * x as bf16 planes.
// Linearity reorder: gather runs on x~ directly; W0 is applied AFTER the
// neighbor sum (sum_k w*(x@W) == (sum_k w*x)@W), so no GEMM here.
// ---------------------------------------------------------------------------
__global__ __launch_bounds__(256) void stage_kernel(
    const float* __restrict__ xf, const float* __restrict__ mask,
    unsigned short* __restrict__ planes, const int* __restrict__ adj,
    const float* __restrict__ wgt, unsigned* __restrict__ edges,
    int nedge, int N, int planeBytes) {
  const int t = threadIdx.x;
  const int base = blockIdx.x * 64;

  // Pack this tile's 2048 edges (8 coalesced iterations).
#pragma unroll
  for (int i = 0; i < 8; ++i) {
    const int ge = base * 32 + i * 256 + t;
    if (ge < nedge) {
      const unsigned id = (unsigned)adj[ge] & 0xffffu;
      const unsigned short h = __builtin_bit_cast(unsigned short, (_Float16)wgt[ge]);
      edges[ge] = id | ((unsigned)h << 16);
    }
  }

  const int node = t >> 2;
  const int sub = t & 3;   // sub == plane index; this thread owns the whole row
  const int gnode = base + node;
  if (gnode >= N) return;
  const float mm = mask[gnode];
  const float s2 = mm * mm;
  const float* src = xf + (size_t)gnode * 128 + sub * 32;
  char* drow = (char*)planes + (size_t)sub * planeBytes + (size_t)gnode * 64;
#pragma unroll
  for (int i = 0; i < 4; ++i) {  // 32 cols -> 4x u32x4 (16B) stores
    const f32x4 a = *(const f32x4*)(src + i * 8);
    const f32x4 b = *(const f32x4*)(src + i * 8 + 4);
    u32x4 pk;
    pk[0] = (unsigned)f2bf(a.x * s2) | ((unsigned)f2bf(a.y * s2) << 16);
    pk[1] = (unsigned)f2bf(a.z * s2) | ((unsigned)f2bf(a.w * s2) << 16);
    pk[2] = (unsigned)f2bf(b.x * s2) | ((unsigned)f2bf(b.y * s2) << 16);
    pk[3] = (unsigned)f2bf(b.z * s2) | ((unsigned)f2bf(b.w * s2) << 16);
    *(u32x4*)(drow + i * 16) = pk;
  }
}

// ---------------------------------------------------------------------------
// gather: block = (tile = bid>>2, plane p = bid&3); bid%8 XCD round-robin
// gives STATIC plane<->XCD affinity (each XCD's L2 holds one 3.2MB plane).
// Proven round-0 form: 16-deep rolling q pipeline, compiler-scheduled
// (request-rate bound at ~44us; forced ILP (r6) and deep fusion (r2/r4)
// both measured worse). Epilogue is now just bf16-pack + store (no
// relu/norm/scal -- moved into the gemm epilogues).
// ---------------------------------------------------------------------------
__global__ __launch_bounds__(256, 3) void gather_kernel(
    const unsigned short* __restrict__ msg, const unsigned* __restrict__ edges,
    unsigned short* __restrict__ gout, int N, int planeBytes) {
  __shared__ unsigned ep[64 * 36];  // stride 36 words: 16B-aligned rows
  const int t = threadIdx.x;
  const int p = blockIdx.x & 3;
  const int nbase = (blockIdx.x >> 2) * 64;

  for (int e = t; e < 64 * 32; e += 256) {
    const int node = e >> 5, k = e & 31;
    const int gn = nbase + node;
    ep[node * 36 + k] = (gn < N) ? edges[(size_t)gn * 32 + k] : 0u;
  }
  __syncthreads();

  const int node = t >> 2;
  const int sub = t & 3;
  const int gnode = nbase + node;
  const unsigned* mp = ep + node * 36;
  const char* plane = (const char*)msg + (size_t)p * planeBytes;
  const int suboff = sub * 16;

  unsigned ew[32];
#pragma unroll
  for (int i = 0; i < 8; ++i)
    *(uint4*)&ew[4 * i] = *(const uint4*)(mp + 4 * i);

  f32x2 acc[4];
#pragma unroll
  for (int d = 0; d < 4; ++d) acc[d] = (f32x2){0.f, 0.f};

  uint4 q[16];
#pragma unroll
  for (int k = 0; k < 16; ++k)
    q[k] = *(const uint4*)(plane + ((size_t)(ew[k] & 0xffffu) * 64 + suboff));

  // consume k, immediately reissue slot k for edge k+16
#pragma unroll
  for (int k = 0; k < 16; ++k) {
    const float w = (float)__builtin_bit_cast(_Float16, (unsigned short)(ew[k] >> 16));
    const f32x2 w2 = {w, w};
    const uint4 qq = q[k];
    q[k] = *(const uint4*)(plane + ((size_t)(ew[16 + k] & 0xffffu) * 64 + suboff));
#pragma unroll
    for (int d = 0; d < 4; ++d) {
      const unsigned qd = (&qq.x)[d];
      f32x2 v2;
      v2.x = __builtin_bit_cast(float, qd << 16);
      v2.y = __builtin_bit_cast(float, qd & 0xffff0000u);
      acc[d] = __builtin_elementwise_fma(v2, w2, acc[d]);
    }
  }
  // drain
#pragma unroll
  for (int k = 0; k < 16; ++k) {
    const float w = (float)__builtin_bit_cast(_Float16,
                                              (unsigned short)(ew[16 + k] >> 16));
    const f32x2 w2 = {w, w};
#pragma unroll
    for (int d = 0; d < 4; ++d) {
      const unsigned qd = (&q[k].x)[d];
      f32x2 v2;
      v2.x = __builtin_bit_cast(float, qd << 16);
      v2.y = __builtin_bit_cast(float, qd & 0xffff0000u);
      acc[d] = __builtin_elementwise_fma(v2, w2, acc[d]);
    }
  }

  if (gnode < N) {
    u32x4 pk4;
#pragma unroll
    for (int d = 0; d < 4; ++d)
      pk4[d] = (unsigned)f2bf(acc[d].x) | ((unsigned)f2bf(acc[d].y) << 16);
    *(u32x4*)((char*)gout + (size_t)p * planeBytes + (size_t)gnode * 64 + suboff) = pk4;
  }
}

// ---------------------------------------------------------------------------
// gemmA: c1 = g1 @ W0 (per-wave 16 rows x 128 cols, full row in registers).
// Epilogue: per-row ||c1||^2 and ||relu(c1)||^2 via in-register + 4x
// shfl_xor (lanes quad*16+m share a row group); then the verified
// exp-map->relu->log-map composite scale sc (identical formula to the old
// gemm1); writes y2~ = sc*relu(c1) bf16 planes for gather2.
// No __syncthreads: per-wave LDS tile region only.
// ---------------------------------------------------------------------------
__global__ __launch_bounds__(256) void gemmA_kernel(
    const unsigned short* __restrict__ g, const float* __restrict__ mask,
    const unsigned short* __restrict__ wpackL, unsigned short* __restrict__ planesOut,
    int N, int planeBytes) {
  __shared__ unsigned short tile[64][136];
  const int lane = threadIdx.x & 63;
  const int wv = threadIdx.x >> 6;
  const int m = lane & 15;
  const int quad = lane >> 4;
  const int wbase = blockIdx.x * 64 + wv * 16;
  const int row = wbase + m;
  const int rowc = row < N ? row : N - 1;

  f32x4 acc[8];
#pragma unroll
  for (int tt = 0; tt < 8; ++tt) acc[tt] = (f32x4){0.f, 0.f, 0.f, 0.f};
#pragma unroll
  for (int sk = 0; sk < 4; ++sk) {
    BF8 a;
    a.q = *(const uint4*)((const char*)g + (size_t)sk * planeBytes +
                          (size_t)rowc * 64 + quad * 16);
#pragma unroll
    for (int tt = 0; tt < 8; ++tt) {
      BF8 b;
      b.q = *(const uint4*)(wpackL + (size_t)((tt * 4 + sk) * 64 + lane) * 8);
      acc[tt] = __builtin_amdgcn_mfma_f32_16x16x32_bf16(a.v, b.v, acc[tt], 0, 0, 0);
    }
  }

  // per-row norms: row (quad, r) spans regs acc[tt][r] over 16 lanes (m)
  float sa[4], sr[4];
#pragma unroll
  for (int r = 0; r < 4; ++r) {
    float a = 0.f, rl = 0.f;
#pragma unroll
    for (int tt = 0; tt < 8; ++tt) {
      const float v = acc[tt][r];
      a = fmaf(v, v, a);
      const float rv = fmaxf(v, 0.f);
      rl = fmaf(rv, rv, rl);
    }
    sa[r] = a;
    sr[r] = rl;
  }
#pragma unroll
  for (int msk = 1; msk < 16; msk <<= 1) {
#pragma unroll
    for (int r = 0; r < 4; ++r) {
      sa[r] += __shfl_xor(sa[r], msk);
      sr[r] += __shfl_xor(sr[r], msk);
    }
  }

  float sc[4];
#pragma unroll
  for (int r = 0; r < 4; ++r) {
    int rr = wbase + quad * 4 + r;
    rr = rr < N ? rr : N - 1;
    const float mm = mask[rr];
    const float s2 = mm * mm * sa[r];
    const float nrm = sqrtf(s2);
    const float ncl = fminf(fmaxf(nrm, EPS), MAX_TANH_ARG);
    const float f1 = tanhf(ncl) / fmaxf(nrm, EPS) * mm * mm * mm;  // x1 = f1*relu(c1)
    const float r2 = f1 * f1 * sr[r];
    const float nr = sqrtf(r2);
    const float nc2 = fminf(fmaxf(nr, EPS), 1.0f - PROJ_EPS);
    const float ls = 0.5f * logf((1.f + nc2) / (1.f - nc2)) / fmaxf(nr, EPS);
    sc[r] = ls * mm * mm * f1;
  }
#pragma unroll
  for (int tt = 0; tt < 8; ++tt) {
    const int c = tt * 16 + m;
#pragma unroll
    for (int r = 0; r < 4; ++r)
      tile[wv * 16 + quad * 4 + r][c] = f2bf(fmaxf(acc[tt][r], 0.f) * sc[r]);
  }
  const int r16 = lane >> 2;
  const int sub2 = lane & 3;
  const int grow = wbase + r16;
  if (grow < N) {
#pragma unroll
    for (int p = 0; p < 4; ++p) {
      *(uint4*)((char*)planesOut + (size_t)p * planeBytes + (size_t)grow * 64 + sub2 * 16) =
          *(const uint4*)((const char*)&tile[wv * 16 + r16][0] + p * 64 + sub2 * 16);
    }
  }
}

// ---------------------------------------------------------------------------
// gemmB: c2 = g2 @ W1 + final exp-map epilogue, fp32 out directly
// (replaces the old gemm1->gather->final tail: out = f2 * relu(c2)).
// Per-wave f32 LDS tile for coalesced 128B/lane output stores.
// ---------------------------------------------------------------------------
__global__ __launch_bounds__(256) void gemmB_kernel(
    const unsigned short* __restrict__ g, const float* __restrict__ mask,
    const unsigned short* __restrict__ wpackL, float* __restrict__ out,
    int N, int planeBytes) {
  __shared__ float otile[64][132];
  const int lane = threadIdx.x & 63;
  const int wv = threadIdx.x >> 6;
  const int m = lane & 15;
  const int quad = lane >> 4;
  const int wbase = blockIdx.x * 64 + wv * 16;
  const int row = wbase + m;
  const int rowc = row < N ? row : N - 1;

  f32x4 acc[8];
#pragma unroll
  for (int tt = 0; tt < 8; ++tt) acc[tt] = (f32x4){0.f, 0.f, 0.f, 0.f};
#pragma unroll
  for (int sk = 0; sk < 4; ++sk) {
    BF8 a;
    a.q = *(const uint4*)((const char*)g + (size_t)sk * planeBytes +
                          (size_t)rowc * 64 + quad * 16);
#pragma unroll
    for (int tt = 0; tt < 8; ++tt) {
      BF8 b;
      b.q = *(const uint4*)(wpackL + (size_t)((tt * 4 + sk) * 64 + lane) * 8);
      acc[tt] = __builtin_amdgcn_mfma_f32_16x16x32_bf16(a.v, b.v, acc[tt], 0, 0, 0);
    }
  }

  float sa[4];
#pragma unroll
  for (int r = 0; r < 4; ++r) {
    float a = 0.f;
#pragma unroll
    for (int tt = 0; tt < 8; ++tt) a = fmaf(acc[tt][r], acc[tt][r], a);
    sa[r] = a;
  }
#pragma unroll
  for (int msk = 1; msk < 16; msk <<= 1) {
#pragma unroll
    for (int r = 0; r < 4; ++r) sa[r] += __shfl_xor(sa[r], msk);
  }

  float f2s[4];
#pragma unroll
  for (int r = 0; r < 4; ++r) {
    int rr = wbase + quad * 4 + r;
    rr = rr < N ? rr : N - 1;
    const float mm = mask[rr];
    const float s2 = mm * mm * sa[r];
    const float nrm = sqrtf(s2);
    const float ncl = fminf(fmaxf(nrm, EPS), MAX_TANH_ARG);
    f2s[r] = tanhf(ncl) / fmaxf(nrm, EPS) * mm * mm * mm;
  }
#pragma unroll
  for (int tt = 0; tt < 8; ++tt) {
    const int c = tt * 16 + m;
#pragma unroll
    for (int r = 0; r < 4; ++r)
      otile[wv * 16 + quad * 4 + r][c] = f2s[r] * fmaxf(acc[tt][r], 0.f);
  }
  const int r16 = lane >> 2;
  const int sub2 = lane & 3;
  const int grow = wbase + r16;
  if (grow < N) {
    float* orow = out + (size_t)grow * 128 + sub2 * 32;
    const float* srow = &otile[wv * 16 + r16][sub2 * 32];
#pragma unroll
    for (int i = 0; i < 8; ++i)
      *(f32x4*)(orow + i * 4) = *(const f32x4*)(srow + i * 4);
  }
}

extern "C" void kernel_launch(void* const* d_in, const int* in_sizes, int n_in,
                              void* d_out, int out_size, void* d_ws, size_t ws_size,
                              hipStream_t stream) {
  const float* node = (const float*)d_in[0];        // [N,128] fp32
  const int* adj = (const int*)d_in[1];             // [N,32] int32
  const float* wgt = (const float*)d_in[2];         // [N,32] fp32
  const float* mask = (const float*)d_in[3];        // [N,1] fp32
  const float* mw = (const float*)d_in[4];          // [2,128,128] fp32
  float* out = (float*)d_out;
  const int N = in_sizes[0] / 128;
  const int gb = (N + 63) / 64;
  const int planeBytes = gb * 64 * 64;
  const int nedge = N * 32;

  // d_out scratch: [0,4*pB) x~/y2~ planes (dead before gemmB's out writes).
  // ws: wpack 64 KiB | g planes (4*pB, g1 then g2) | edges (4B*nedge).
  unsigned short* xyplanes = (unsigned short*)d_out;
  unsigned short* wpack = (unsigned short*)d_ws;
  unsigned short* gplanes = (unsigned short*)((char*)d_ws + 65536);
  unsigned* edges = (unsigned*)((char*)d_ws + 65536 + (size_t)4 * planeBytes);

  hipLaunchKernelGGL(prep_kernel, dim3(16), dim3(256), 0, stream, mw, wpack);
  hipLaunchKernelGGL(stage_kernel, dim3(gb), dim3(256), 0, stream,
                     node, mask, xyplanes, adj, wgt, edges, nedge, N, planeBytes);
  hipLaunchKernelGGL(gather_kernel, dim3(gb * 4), dim3(256), 0, stream,
                     xyplanes, edges, gplanes, N, planeBytes);
  hipLaunchKernelGGL(gemmA_kernel, dim3(gb), dim3(256), 0, stream,
                     gplanes, mask, wpack, xyplanes, N, planeBytes);
  hipLaunchKernelGGL(gather_kernel, dim3(gb * 4), dim3(256), 0, stream,
                     xyplanes, edges, gplanes, N, planeBytes);
  hipLaunchKernelGGL(gemmB_kernel, dim3(gb), dim3(256), 0, stream,
                     gplanes, mask, wpack + 16384, out, N, planeBytes);
}